// Round 14
// baseline (512.356 us; speedup 1.0000x reference)
//
#include <hip/hip_runtime.h>
#include <math.h>

#define NN 10000
#define NE 160000
#define E2 (NE + NN)
#define NG 20
#define MPAD 10240   // 40 * 256
#define NSPLIT 8

typedef __attribute__((ext_vector_type(8))) short short8;
typedef __attribute__((ext_vector_type(4))) float f32x4;
typedef __attribute__((ext_vector_type(4))) unsigned short us4;

// ---------- helpers ----------
__device__ inline unsigned short f2bf(float f){
  unsigned u = __float_as_uint(f);
  unsigned r = u + 0x7FFFu + ((u >> 16) & 1u);
  return (unsigned short)(r >> 16);
}
__device__ inline float bf2f(unsigned short h){ return __uint_as_float(((unsigned)h) << 16); }

__device__ inline void gload_lds16(const void* g, void* l){
  __builtin_amdgcn_global_load_lds((const __attribute__((address_space(1))) void*)g,
                                   (__attribute__((address_space(3))) void*)l, 16, 0, 0);
}

// ---------- graph boundary (batch is sorted) ----------
__global__ void k_gptr(const int* __restrict__ batch, int* __restrict__ gptr){
  int g = threadIdx.x;
  if (g > NG) return;
  int lo = 0, hi = NN;
  while (lo < hi){ int mid = (lo+hi)>>1; if (batch[mid] < g) lo = mid+1; else hi = mid; }
  gptr[g] = lo;
}

// ---------- CSR build (by dst, self-loops appended) ----------
__global__ void k_count(const int* __restrict__ ei, int* __restrict__ cnt){
  int e = blockIdx.x*256 + threadIdx.x;
  if (e >= E2) return;
  int d = (e < NE) ? ei[NE + e] : (e - NE);
  atomicAdd(&cnt[d], 1);
}

__global__ void k_scan(const int* __restrict__ cnt, int* __restrict__ ptr){
  __shared__ int tpre[256];
  __shared__ int tsum[256];
  int tid = threadIdx.x;
  const int per = (NN + 255)/256;
  int base = tid*per;
  int s = 0;
  for (int i=0;i<per;i++){ int idx=base+i; if (idx<NN) s += cnt[idx]; }
  tsum[tid] = s;
  __syncthreads();
  if (tid == 0){
    int run = 0;
    for (int i=0;i<256;i++){ tpre[i]=run; run += tsum[i]; }
    ptr[NN] = run;
  }
  __syncthreads();
  int run = tpre[tid];
  for (int i=0;i<per;i++){ int idx=base+i; if (idx<NN){ ptr[idx]=run; run += cnt[idx]; } }
}

__global__ void k_copy(const int* __restrict__ src, int* __restrict__ dst){
  int i = blockIdx.x*256 + threadIdx.x;
  if (i < NN) dst[i] = src[i];
}

__global__ void k_scatter(const int* __restrict__ ei, int* __restrict__ fill, int* __restrict__ csrc){
  int e = blockIdx.x*256 + threadIdx.x;
  if (e >= E2) return;
  int s, d;
  if (e < NE){ s = ei[e]; d = ei[NE + e]; } else { s = d = e - NE; }
  int pos = atomicAdd(&fill[d], 1);
  csrc[pos] = s;
}

// ---------- conversions ----------
__global__ void k_xconv(const float* __restrict__ x, unsigned short* __restrict__ xbf){
  int i = blockIdx.x*256 + threadIdx.x;
  if (i >= MPAD*64) return;
  int r = i >> 6, c = i & 63;
  float v = (r < NN && c < 50) ? x[r*50 + c] : 0.f;
  xbf[i] = f2bf(v);
}

// all four W -> transposed bf16 (zero-padded), single kernel
#define WT0 0
#define WT1 65536
#define WT2 1114112
#define WT3 2162688
#define WTT 2293760
__global__ void k_wconvall(const float* __restrict__ W0, const float* __restrict__ W1,
                           const float* __restrict__ W2, const float* __restrict__ W3,
                           unsigned short* __restrict__ wt){
  int i = blockIdx.x*256 + threadIdx.x;
  if (i >= WTT) return;
  const float* W; int K, N, Kpad, off;
  if (i < WT1){ W=W0; K=50; N=1024; Kpad=64; off=WT0; }
  else if (i < WT2){ W=W1; K=1024; N=1024; Kpad=1024; off=WT1; }
  else if (i < WT3){ W=W2; K=1024; N=1024; Kpad=1024; off=WT2; }
  else { W=W3; K=1024; N=121; Kpad=1024; off=WT3; }
  int j = i - off;
  int nn = j / Kpad, kk = j - nn*Kpad;
  float v = (nn < N && kk < K) ? W[(size_t)kk*N + nn] : 0.f;
  wt[i] = f2bf(v);
}

// pad layer-4 att vectors 121 -> 128
__global__ void k_attpad4(const float* __restrict__ AS3, const float* __restrict__ AD3,
                          float* __restrict__ asp4, float* __restrict__ adp4){
  int i = threadIdx.x;   // 128
  asp4[i] = (i < 121) ? AS3[i] : 0.f;
  adp4[i] = (i < 121) ? AD3[i] : 0.f;
}

// ---------- bf16 MFMA GEMM: 256xTBN tile, 512 threads ----------
// 8 waves (2 row x 4 col), wave tile 128 x TBN/4 (squarest = best LDS reuse).
// 4-buffer LDS, depth-3 counted-vmcnt prefetch, ONE barrier per K-step, NO
// explicit lgkmcnt (compiler interleaves ds_read with MFMA). Epilogue: fused
// attention halves block-locally, no atomics.
template<int TBN>
__global__ __launch_bounds__(512, 2) void k_gemm256(
    const unsigned short* __restrict__ A,
    const unsigned short* __restrict__ Bt,
    unsigned short* __restrict__ Cbf,
    const float* __restrict__ asp, const float* __restrict__ adp,
    float* __restrict__ a_s, float* __restrict__ a_d,
    int M, int K, int FS, int ncb, int H)
{
  constexpr int MFR = 8;
  constexpr int NFR = TBN/64;
  constexpr int ABYTES = 256*64;
  constexpr int BBYTES = TBN*64;
  constexpr int AINST = 2;
  constexpr int BINST = TBN/128;
  constexpr int LPS = AINST + BINST;   // 4 (TBN=256) or 3 (TBN=128)
  __shared__ unsigned short sA[4*256*32];
  __shared__ unsigned short sB[4*TBN*32];
  const int tid = threadIdx.x;
  const int wave = tid >> 6;
  const int lane = tid & 63;
  const int nwg = gridDim.x;
  const int q = nwg >> 3, rmod = nwg & 7;
  const int xcd = blockIdx.x & 7, idx = blockIdx.x >> 3;
  const int wg = (xcd < rmod) ? (xcd*(q+1) + idx) : (rmod*(q+1) + (xcd - rmod)*q + idx);
  const int rowt = wg / ncb;
  const int colt = wg - rowt*ncb;
  const int row0 = rowt * 256;
  const int col0 = colt * TBN;
  const int wr = (wave >> 2) * 128;
  const int wc = (wave & 3) * (TBN/4);
  f32x4 acc[MFR][NFR];
  #pragma unroll
  for (int i=0;i<MFR;i++)
    #pragma unroll
    for (int j=0;j<NFR;j++){ acc[i][j][0]=0.f; acc[i][j][1]=0.f; acc[i][j][2]=0.f; acc[i][j][3]=0.f; }

  const unsigned short* aP[AINST];
  int aL[AINST];
  #pragma unroll
  for (int i=0;i<AINST;i++){
    int s = (wave*AINST + i)*64 + lane;
    int row = s >> 2, chn = (s & 3) ^ ((row >> 1) & 3);
    aP[i] = A + (size_t)(row0 + row)*K + chn*8;
    aL[i] = (wave*AINST + i)*1024;
  }
  const unsigned short* bP[BINST];
  int bL[BINST];
  #pragma unroll
  for (int i=0;i<BINST;i++){
    int s = (wave*BINST + i)*64 + lane;
    int row = s >> 2, chn = (s & 3) ^ ((row >> 1) & 3);
    bP[i] = Bt + (size_t)(col0 + row)*K + chn*8;
    bL[i] = (wave*BINST + i)*1024;
  }
  char* ldsA = (char*)sA;
  char* ldsB = (char*)sB;

  auto STAGE = [&](int k0, int buf){
    #pragma unroll
    for (int i=0;i<AINST;i++) gload_lds16(aP[i] + k0, ldsA + buf*ABYTES + aL[i]);
    #pragma unroll
    for (int i=0;i<BINST;i++) gload_lds16(bP[i] + k0, ldsB + buf*BBYTES + bL[i]);
  };

  const int NT = K >> 5;
  const int kch = lane >> 4;
  const int rlo = lane & 15;

  STAGE(0, 0);
  if (NT > 1) STAGE(32, 1);
  if (NT > 2) STAGE(64, 2);

  int cur = 0;
  for (int t = 0; t < NT; ++t){
    // wait this tile's loads (mine) -> barrier makes all waves' loads visible.
    if (t+2 < NT){
      if constexpr (LPS==4) asm volatile("s_waitcnt vmcnt(8)" ::: "memory");
      else                  asm volatile("s_waitcnt vmcnt(6)" ::: "memory");
    } else if (t+1 < NT){
      if constexpr (LPS==4) asm volatile("s_waitcnt vmcnt(4)" ::: "memory");
      else                  asm volatile("s_waitcnt vmcnt(3)" ::: "memory");
    } else {
      asm volatile("s_waitcnt vmcnt(0)" ::: "memory");
    }
    __builtin_amdgcn_s_barrier();
    __builtin_amdgcn_sched_barrier(0);   // nothing crosses above the barrier
    const unsigned short* bA = sA + cur*(256*32);
    const unsigned short* bB = sB + cur*(TBN*32);
    // prefetch stage t+3 (buffer (cur+3)&3 was read at t-1; barrier protects)
    if (t+3 < NT){
      STAGE((t+3) << 5, (cur+3)&3);
    }
    short8 af[MFR], bfr[NFR];
    #pragma unroll
    for (int m=0;m<MFR;m++){
      int r = wr + m*16 + rlo;
      af[m] = *(const short8*)(bA + r*32 + ((kch ^ ((r>>1)&3))<<3));
    }
    #pragma unroll
    for (int n=0;n<NFR;n++){
      int r = wc + n*16 + rlo;
      bfr[n] = *(const short8*)(bB + r*32 + ((kch ^ ((r>>1)&3))<<3));
    }
    __builtin_amdgcn_s_setprio(1);
    #pragma unroll
    for (int m=0;m<MFR;m++)
      #pragma unroll
      for (int n=0;n<NFR;n++)
        acc[m][n] = __builtin_amdgcn_mfma_f32_16x16x32_bf16(af[m], bfr[n], acc[m][n], 0, 0, 0);
    __builtin_amdgcn_s_setprio(0);
    cur = (cur+1)&3;
  }
  const int cr = (lane >> 4) * 4;
  const int cc = lane & 15;
  // C store (bf16)
  #pragma unroll
  for (int m=0;m<MFR;m++){
    #pragma unroll
    for (int n=0;n<NFR;n++){
      int col = col0 + wc + n*16 + cc;
      #pragma unroll
      for (int r=0;r<4;r++){
        int row = row0 + wr + m*16 + cr + r;
        if (row < M) Cbf[(size_t)row*FS + col] = f2bf(acc[m][n][r]);
      }
    }
  }
  // fused attention halves: block-local (col-tile == full head for TBN=256;
  // for L4 TBN=128 the whole 128-col tile is the single head).
  float asv[NFR], adv[NFR];
  #pragma unroll
  for (int n=0;n<NFR;n++){
    int col = col0 + wc + n*16 + cc;
    asv[n] = asp[col]; adv[n] = adp[col];
  }
  __syncthreads();
  float* part = (float*)sA;        // [2][128][4][2] = 8 KB
  #pragma unroll
  for (int m=0;m<MFR;m++){
    #pragma unroll
    for (int r=0;r<4;r++){
      float ss = 0.f, sd = 0.f;
      #pragma unroll
      for (int n=0;n<NFR;n++){ float v = acc[m][n][r]; ss += v*asv[n]; sd += v*adv[n]; }
      #pragma unroll
      for (int o=8;o;o>>=1){ ss += __shfl_xor(ss,o); sd += __shfl_xor(sd,o); }
      if (cc == 0){
        int rowLocal = m*16 + cr + r;
        int pidx = ((wave>>2)*128 + rowLocal)*8 + (wave&3)*2;
        part[pidx] = ss; part[pidx+1] = sd;
      }
    }
  }
  __syncthreads();
  {
    int row = tid >> 1, v = tid & 1;   // 512 threads = 256 rows x 2
    int base = row*8 + v;
    float s = part[base] + part[base+2] + part[base+4] + part[base+6];
    int grow = row0 + row;
    const int head = colt;
    if (grow < M){
      if (v) a_d[grow*H + head] = s;
      else   a_s[grow*H + head] = s;
    }
  }
}

// ---------- fused softmax + gather, wave-per-node (F=1024, H=4, FS=1024) ----------
// 2-edge ping-pong prefetch (R12 version: best measured).
__global__ __launch_bounds__(256) void k_gatherw(
    const unsigned short* __restrict__ h,
    const float* __restrict__ a_s, const float* __restrict__ a_d,
    const int* __restrict__ ptr, const int* __restrict__ csrc,
    const float* __restrict__ bias, float* __restrict__ out)
{
  __shared__ float sal[4][64*4];
  __shared__ int ssn[4][64];
  const int wid = threadIdx.x >> 6, lane = threadIdx.x & 63;
  const int node = blockIdx.x*4 + wid;
  const int hh = lane >> 4;
  const int beg = ptr[node], deg = ptr[node+1] - beg;
  f32x4 ad4 = *(const f32x4*)(a_d + node*4);
  float acc[16], acc2[16];
  #pragma unroll
  for (int j=0;j<16;j++){ acc[j]=0.f; acc2[j]=0.f; }
  f32x4 denp = {0.f,0.f,0.f,0.f};
  const unsigned short* hb = h + lane*16;

  for (int c0 = 0; c0 < deg; c0 += 64){
    int n = min(64, deg - c0);
    if (lane < n){
      int s = csrc[beg + c0 + lane];
      f32x4 as4 = *(const f32x4*)(a_s + s*4);
      f32x4 e4;
      #pragma unroll
      for (int k2=0;k2<4;k2++){
        float ev = as4[k2] + ad4[k2];
        ev = ev > 0.f ? ev : 0.2f*ev;
        float x = __expf(ev);
        e4[k2] = x;
        denp[k2] += x;
      }
      *(f32x4*)&sal[wid][lane*4] = e4;
      ssn[wid][lane] = s;
    }
    int e = 0;
    if (n >= 2){
      int s0 = ssn[wid][0], s1 = ssn[wid][1];
      float aA = sal[wid][hh], aB = sal[wid][4+hh];
      const unsigned short* p0 = hb + (size_t)s0*1024;
      const unsigned short* p1 = hb + (size_t)s1*1024;
      short8 ca0=*(const short8*)p0, ca1=*(const short8*)(p0+8);
      short8 cb0=*(const short8*)p1, cb1=*(const short8*)(p1+8);
      for (e = 0; e+3 < n; e += 2){
        int s2 = ssn[wid][e+2], s3 = ssn[wid][e+3];
        float nA = sal[wid][(e+2)*4+hh], nB = sal[wid][(e+3)*4+hh];
        const unsigned short* p2 = hb + (size_t)s2*1024;
        const unsigned short* p3 = hb + (size_t)s3*1024;
        short8 na0=*(const short8*)p2, na1=*(const short8*)(p2+8);
        short8 nb0=*(const short8*)p3, nb1=*(const short8*)(p3+8);
        #pragma unroll
        for (int j=0;j<8;j++){ acc[j]   += bf2f((unsigned short)ca0[j])*aA;
                               acc[8+j] += bf2f((unsigned short)ca1[j])*aA; }
        #pragma unroll
        for (int j=0;j<8;j++){ acc2[j]   += bf2f((unsigned short)cb0[j])*aB;
                               acc2[8+j] += bf2f((unsigned short)cb1[j])*aB; }
        ca0=na0; ca1=na1; cb0=nb0; cb1=nb1; aA=nA; aB=nB;
      }
      #pragma unroll
      for (int j=0;j<8;j++){ acc[j]   += bf2f((unsigned short)ca0[j])*aA;
                             acc[8+j] += bf2f((unsigned short)ca1[j])*aA; }
      #pragma unroll
      for (int j=0;j<8;j++){ acc2[j]   += bf2f((unsigned short)cb0[j])*aB;
                             acc2[8+j] += bf2f((unsigned short)cb1[j])*aB; }
      e += 2;
    }
    for (; e < n; ++e){
      int s = ssn[wid][e];
      float al = sal[wid][e*4 + hh];
      const unsigned short* p = hb + (size_t)s*1024;
      short8 u0 = *(const short8*)p, u1 = *(const short8*)(p+8);
      #pragma unroll
      for (int j=0;j<8;j++){ acc[j]   += bf2f((unsigned short)u0[j])*al;
                             acc[8+j] += bf2f((unsigned short)u1[j])*al; }
    }
  }
  #pragma unroll
  for (int o=32;o;o>>=1){
    #pragma unroll
    for (int k2=0;k2<4;k2++) denp[k2] += __shfl_xor(denp[k2], o);
  }
  float inv = 1.f / (denp[hh] + 1e-16f);
  float* op = out + (size_t)node*1024 + lane*16;
  const float* bp = bias + lane*16;
  #pragma unroll
  for (int j=0;j<16;j++) op[j] = (acc[j]+acc2[j])*inv + bp[j];
}

// ---------- fused softmax + gather, wave-per-node (layer 4: F=121, FS=128) ----------
__global__ __launch_bounds__(256) void k_gatherw1(
    const unsigned short* __restrict__ h,
    const float* __restrict__ a_s, const float* __restrict__ a_d,
    const int* __restrict__ ptr, const int* __restrict__ csrc,
    const float* __restrict__ bias, float* __restrict__ out)
{
  __shared__ float sal[4][64];
  __shared__ int ssn[4][64];
  const int wid = threadIdx.x >> 6, lane = threadIdx.x & 63;
  const int node = blockIdx.x*4 + wid;
  const int beg = ptr[node], deg = ptr[node+1] - beg;
  float ad = a_d[node];
  float den = 0.f;
  float acc[2] = {0.f,0.f}, acc2[2] = {0.f,0.f};
  const int c0i = lane*2;
  const unsigned short* hb = h + c0i;

  for (int b0 = 0; b0 < deg; b0 += 64){
    int n = min(64, deg - b0);
    if (lane < n){
      int s = csrc[beg + b0 + lane];
      float ev = a_s[s] + ad;
      ev = ev > 0.f ? ev : 0.2f*ev;
      float x = __expf(ev);
      sal[wid][lane] = x;
      ssn[wid][lane] = s;
      den += x;
    }
    int e = 0;
    for (; e + 1 < n; e += 2){
      int sA_ = ssn[wid][e], sB_ = ssn[wid][e+1];
      float aA = sal[wid][e], aB = sal[wid][e+1];
      const unsigned short* pA = hb + (size_t)sA_*128;
      const unsigned short* pB = hb + (size_t)sB_*128;
      acc[0]  += bf2f(pA[0])*aA; acc[1]  += bf2f(pA[1])*aA;
      acc2[0] += bf2f(pB[0])*aB; acc2[1] += bf2f(pB[1])*aB;
    }
    if (e < n){
      int sA_ = ssn[wid][e];
      float aA = sal[wid][e];
      const unsigned short* pA = hb + (size_t)sA_*128;
      acc[0] += bf2f(pA[0])*aA; acc[1] += bf2f(pA[1])*aA;
    }
  }
  #pragma unroll
  for (int o=32;o;o>>=1) den += __shfl_xor(den, o);
  float inv = 1.f / (den + 1e-16f);
  if (c0i < 121)   out[(size_t)node*121 + c0i]   = (acc[0]+acc2[0])*inv + bias[c0i];
  if (c0i+1 < 121) out[(size_t)node*121 + c0i+1] = (acc[1]+acc2[1])*inv + bias[c0i+1];
}

// ---------- GraphNorm stats (vectorized partials) / coefs / apply+ELU ----------
__global__ void k_gnstats(const float* __restrict__ x, const int* __restrict__ gptr,
                          float* __restrict__ psum, float* __restrict__ psq){
  int g = blockIdx.x, sp = blockIdx.z;
  int c4 = threadIdx.x*4;
  int beg = gptr[g], end = gptr[g+1];
  int n = end - beg;
  int per = (n + NSPLIT - 1) / NSPLIT;
  int nb = beg + sp*per, ne = min(end, nb + per);
  f32x4 s = {0.f,0.f,0.f,0.f}, qv = {0.f,0.f,0.f,0.f};
  for (int i = nb; i < ne; i++){
    f32x4 v = *(const f32x4*)(x + (size_t)i*1024 + c4);
    s += v; qv += v*v;
  }
  int idx = (sp*NG + g)*1024 + c4;
  *(f32x4*)(psum + idx) = s;
  *(f32x4*)(psq + idx) = qv;
}

__global__ void k_coef(const float* __restrict__ psum, const float* __restrict__ psq,
                       const int* __restrict__ gptr,
                       const float* __restrict__ w, const float* __restrict__ b, const float* __restrict__ ms,
                       float* __restrict__ cA, float* __restrict__ cB){
  int i = blockIdx.x*256 + threadIdx.x;
  if (i >= NG*1024) return;
  int g = i >> 10, c = i & 1023;
  float cntf = (float)(gptr[g+1] - gptr[g]);
  float sm = 0.f, sq = 0.f;
  #pragma unroll
  for (int sp=0; sp<NSPLIT; sp++){
    sm += psum[(sp*NG + g)*1024 + c];
    sq += psq[(sp*NG + g)*1024 + c];
  }
  float m = sm / cntf;
  float s = ms[c];
  float ex2 = sq / cntf;
  float var = ex2 - 2.f*s*m*m + s*s*m*m;
  float inv = rsqrtf(var + 1e-5f);
  float wa = w[c]*inv;
  cA[i] = wa;
  cB[i] = b[c] - wa*m*s;
}

__global__ void k_applyelu(const float* __restrict__ x, const int* __restrict__ batch,
                           const float* __restrict__ cA, const float* __restrict__ cB,
                           unsigned short* __restrict__ obf){
  int i = blockIdx.x*256 + threadIdx.x;        // over NN*256
  if (i >= NN*256) return;
  int node = i >> 8;
  int c4 = (i & 255)*4;
  int g = batch[node];
  f32x4 v = *(const f32x4*)(x + (size_t)node*1024 + c4);
  f32x4 a = *(const f32x4*)(cA + g*1024 + c4);
  f32x4 b = *(const f32x4*)(cB + g*1024 + c4);
  us4 o;
  #pragma unroll
  for (int j=0;j<4;j++){
    float y = a[j]*v[j] + b[j];
    y = y > 0.f ? y : expm1f(y);
    o[j] = f2bf(y);
  }
  *(us4*)(obf + (size_t)node*1024 + c4) = o;
}

// ---------- orchestration ----------
extern "C" void kernel_launch(void* const* d_in, const int* in_sizes, int n_in,
                              void* d_out, int out_size, void* d_ws, size_t ws_size,
                              hipStream_t stream){
  (void)in_sizes; (void)n_in; (void)out_size; (void)ws_size;
  const float* x     = (const float*)d_in[0];
  const int*   ei    = (const int*)d_in[1];
  const int*   batch = (const int*)d_in[2];
  const float* W[4]  = {(const float*)d_in[3],  (const float*)d_in[7],  (const float*)d_in[11], (const float*)d_in[15]};
  const float* AS[4] = {(const float*)d_in[4],  (const float*)d_in[8],  (const float*)d_in[12], (const float*)d_in[16]};
  const float* AD[4] = {(const float*)d_in[5],  (const float*)d_in[9],  (const float*)d_in[13], (const float*)d_in[17]};
  const float* BI[4] = {(const float*)d_in[6],  (const float*)d_in[10], (const float*)d_in[14], (const float*)d_in[18]};
  const float* GW[3] = {(const float*)d_in[19], (const float*)d_in[22], (const float*)d_in[25]};
  const float* GB[3] = {(const float*)d_in[20], (const float*)d_in[23], (const float*)d_in[26]};
  const float* GA[3] = {(const float*)d_in[21], (const float*)d_in[24], (const float*)d_in[27]};

  float* ws   = (float*)d_ws;
  float* bufB = ws;                                  // [NN,1024] f32
  float* a_s  = bufB + (size_t)NN*1024;              // [NN,4]
  float* a_d  = a_s + (size_t)NN*4;                  // [NN,4]
  float* psum = a_d + (size_t)NN*4;                  // [NSPLIT,NG,1024]
  float* psq  = psum + (size_t)NSPLIT*NG*1024;       // [NSPLIT,NG,1024]
  float* cA   = psq  + (size_t)NSPLIT*NG*1024;       // [NG,1024]
  float* cB   = cA   + (size_t)NG*1024;              // [NG,1024]
  float* asp4 = cB   + (size_t)NG*1024;              // [128]
  float* adp4 = asp4 + 128;                          // [128]
  int* ptr  = (int*)(adp4 + 128);                    // [NN+1]
  int* fill = ptr + (NN + 8);                        // [NN+1]
  int* csrc = fill + (NN + 8);                       // [E2]
  int* gptr = csrc + E2;                             // [NG+1] (pad 24)
  unsigned short* abf = (unsigned short*)(gptr + 24);// [MPAD,1024] bf16 (xbf aliases start)
  unsigned short* xbf = abf;                         // [MPAD,64] bf16 (dead after L0 gemm)
  unsigned short* hbf = abf + (size_t)MPAD*1024;     // [NN,1024] bf16
  unsigned short* wt  = hbf + (size_t)NN*1024;       // [WTT] bf16 (all 4 layers)

  hipMemsetAsync(fill, 0, sizeof(int)*(NN+1), stream);
  k_gptr<<<1, 32, 0, stream>>>(batch, gptr);
  k_count<<<(E2+255)/256, 256, 0, stream>>>(ei, fill);
  k_scan<<<1, 256, 0, stream>>>(fill, ptr);
  k_copy<<<(NN+255)/256, 256, 0, stream>>>(ptr, fill);
  k_scatter<<<(E2+255)/256, 256, 0, stream>>>(ei, fill, csrc);
  k_xconv<<<(MPAD*64+255)/256, 256, 0, stream>>>(x, xbf);
  k_wconvall<<<(WTT+255)/256, 256, 0, stream>>>(W[0], W[1], W[2], W[3], wt);
  k_attpad4<<<1, 128, 0, stream>>>(AS[3], AD[3], asp4, adp4);

  const int Kp[4]  = {64, 1024, 1024, 1024};
  const int Np[4]  = {1024, 1024, 1024, 128};
  const int Woff[4] = {WT0, WT1, WT2, WT3};
  for (int li = 0; li < 4; ++li){
    int FS = Np[li];
    const unsigned short* Ain = (li == 0) ? xbf : abf;
    const unsigned short* Wt = wt + Woff[li];
    if (li < 3){
      int ncb = 4;
      int nwg = (MPAD/256) * ncb;          // 160 blocks (<=1 per CU)
      k_gemm256<256><<<nwg, 512, 0, stream>>>(Ain, Wt, hbf, AS[li], AD[li], a_s, a_d,
                                              NN, Kp[li], FS, ncb, 4);
      k_gatherw<<<NN/4, 256, 0, stream>>>(hbf, a_s, a_d, ptr, csrc, BI[li], bufB);
      k_gnstats<<<dim3(NG, 1, NSPLIT), 256, 0, stream>>>(bufB, gptr, psum, psq);
      k_coef<<<(NG*1024 + 255)/256, 256, 0, stream>>>(psum, psq, gptr, GW[li], GB[li], GA[li], cA, cB);
      k_applyelu<<<(NN*256 + 255)/256, 256, 0, stream>>>(bufB, batch, cA, cB, abf);
    } else {
      int ncb = 1;
      int nwg = (MPAD/256) * ncb;          // 40 blocks
      k_gemm256<128><<<nwg, 512, 0, stream>>>(Ain, Wt, hbf, asp4, adp4, a_s, a_d,
                                              NN, Kp[li], FS, ncb, 1);
      k_gatherw1<<<NN/4, 256, 0, stream>>>(hbf, a_s, a_d, ptr, csrc, BI[li], (float*)d_out);
    }
  }
}

// Round 15
// 482.431 us; speedup vs baseline: 1.0620x; 1.0620x over previous
//
#include <hip/hip_runtime.h>
#include <math.h>

#define NN 10000
#define NE 160000
#define E2 (NE + NN)
#define NG 20
#define MPAD 10240   // 80*128 = 40*256
#define NSPLIT 8

typedef __attribute__((ext_vector_type(8))) short short8;
typedef __attribute__((ext_vector_type(4))) float f32x4;
typedef __attribute__((ext_vector_type(4))) unsigned short us4;

// ---------- helpers ----------
__device__ inline unsigned short f2bf(float f){
  unsigned u = __float_as_uint(f);
  unsigned r = u + 0x7FFFu + ((u >> 16) & 1u);
  return (unsigned short)(r >> 16);
}
__device__ inline float bf2f(unsigned short h){ return __uint_as_float(((unsigned)h) << 16); }

__device__ inline void gload_lds16(const void* g, void* l){
  __builtin_amdgcn_global_load_lds((const __attribute__((address_space(1))) void*)g,
                                   (__attribute__((address_space(3))) void*)l, 16, 0, 0);
}

// ---------- graph boundary (batch is sorted) ----------
__global__ void k_gptr(const int* __restrict__ batch, int* __restrict__ gptr){
  int g = threadIdx.x;
  if (g > NG) return;
  int lo = 0, hi = NN;
  while (lo < hi){ int mid = (lo+hi)>>1; if (batch[mid] < g) lo = mid+1; else hi = mid; }
  gptr[g] = lo;
}

// ---------- CSR build (by dst, self-loops appended) ----------
__global__ void k_count(const int* __restrict__ ei, int* __restrict__ cnt){
  int e = blockIdx.x*256 + threadIdx.x;
  if (e >= E2) return;
  int d = (e < NE) ? ei[NE + e] : (e - NE);
  atomicAdd(&cnt[d], 1);
}

__global__ void k_scan(const int* __restrict__ cnt, int* __restrict__ ptr){
  __shared__ int tpre[256];
  __shared__ int tsum[256];
  int tid = threadIdx.x;
  const int per = (NN + 255)/256;
  int base = tid*per;
  int s = 0;
  for (int i=0;i<per;i++){ int idx=base+i; if (idx<NN) s += cnt[idx]; }
  tsum[tid] = s;
  __syncthreads();
  if (tid == 0){
    int run = 0;
    for (int i=0;i<256;i++){ tpre[i]=run; run += tsum[i]; }
    ptr[NN] = run;
  }
  __syncthreads();
  int run = tpre[tid];
  for (int i=0;i<per;i++){ int idx=base+i; if (idx<NN){ ptr[idx]=run; run += cnt[idx]; } }
}

__global__ void k_copy(const int* __restrict__ src, int* __restrict__ dst){
  int i = blockIdx.x*256 + threadIdx.x;
  if (i < NN) dst[i] = src[i];
}

__global__ void k_scatter(const int* __restrict__ ei, int* __restrict__ fill, int* __restrict__ csrc){
  int e = blockIdx.x*256 + threadIdx.x;
  if (e >= E2) return;
  int s, d;
  if (e < NE){ s = ei[e]; d = ei[NE + e]; } else { s = d = e - NE; }
  int pos = atomicAdd(&fill[d], 1);
  csrc[pos] = s;
}

// ---------- conversions ----------
__global__ void k_xconv(const float* __restrict__ x, unsigned short* __restrict__ xbf){
  int i = blockIdx.x*256 + threadIdx.x;
  if (i >= MPAD*64) return;
  int r = i >> 6, c = i & 63;
  float v = (r < NN && c < 50) ? x[r*50 + c] : 0.f;
  xbf[i] = f2bf(v);
}

// all four W -> transposed bf16 (zero-padded), single kernel
#define WT0 0
#define WT1 65536
#define WT2 1114112
#define WT3 2162688
#define WTT 2293760
__global__ void k_wconvall(const float* __restrict__ W0, const float* __restrict__ W1,
                           const float* __restrict__ W2, const float* __restrict__ W3,
                           unsigned short* __restrict__ wt){
  int i = blockIdx.x*256 + threadIdx.x;
  if (i >= WTT) return;
  const float* W; int K, N, Kpad, off;
  if (i < WT1){ W=W0; K=50; N=1024; Kpad=64; off=WT0; }
  else if (i < WT2){ W=W1; K=1024; N=1024; Kpad=1024; off=WT1; }
  else if (i < WT3){ W=W2; K=1024; N=1024; Kpad=1024; off=WT2; }
  else { W=W3; K=1024; N=121; Kpad=1024; off=WT3; }
  int j = i - off;
  int nn = j / Kpad, kk = j - nn*Kpad;
  float v = (nn < N && kk < K) ? W[(size_t)kk*N + nn] : 0.f;
  wt[i] = f2bf(v);
}

// pad layer-4 att vectors 121 -> 128
__global__ void k_attpad4(const float* __restrict__ AS3, const float* __restrict__ AD3,
                          float* __restrict__ asp4, float* __restrict__ adp4){
  int i = threadIdx.x;   // 128
  asp4[i] = (i < 121) ? AS3[i] : 0.f;
  adp4[i] = (i < 121) ? AD3[i] : 0.f;
}

// ---------- bf16 MFMA GEMM: TBM x TBN tile, 512 threads (8 waves, 2x4) ----------
// R12's measured-best schedule: 3-buffer LDS, lgkmcnt drain + counted vmcnt,
// one barrier per K-step, chunk-swizzled LDS. Epilogue: block-local fused
// attention halves (col-tile == one full head), plain stores, no atomics.
template<int TBM, int TBN>
__global__ __launch_bounds__(512, 4) void k_gemm256(
    const unsigned short* __restrict__ A,
    const unsigned short* __restrict__ Bt,
    unsigned short* __restrict__ Cbf,
    const float* __restrict__ asp, const float* __restrict__ adp,
    float* __restrict__ a_s, float* __restrict__ a_d,
    int M, int K, int FS, int ncb, int H)
{
  constexpr int MFR = TBM/32;
  constexpr int NFR = TBN/64;
  constexpr int ABYTES = TBM*64;
  constexpr int BBYTES = TBN*64;
  constexpr int AINST = TBM/128;
  constexpr int BINST = TBN/128;
  constexpr int LPS = AINST + BINST;   // 3 for both 128x256 and 256x128
  __shared__ unsigned short sA[3*TBM*32];
  __shared__ unsigned short sB[3*TBN*32];
  const int tid = threadIdx.x;
  const int wave = tid >> 6;
  const int lane = tid & 63;
  const int nwg = gridDim.x;
  const int q = nwg >> 3, rmod = nwg & 7;
  const int xcd = blockIdx.x & 7, idx = blockIdx.x >> 3;
  const int wg = (xcd < rmod) ? (xcd*(q+1) + idx) : (rmod*(q+1) + (xcd - rmod)*q + idx);
  const int rowt = wg / ncb;
  const int colt = wg - rowt*ncb;
  const int row0 = rowt * TBM;
  const int col0 = colt * TBN;
  const int wr = (wave >> 2) * (TBM/2);
  const int wc = (wave & 3) * (TBN/4);
  f32x4 acc[MFR][NFR];
  #pragma unroll
  for (int i=0;i<MFR;i++)
    #pragma unroll
    for (int j=0;j<NFR;j++){ acc[i][j][0]=0.f; acc[i][j][1]=0.f; acc[i][j][2]=0.f; acc[i][j][3]=0.f; }

  const unsigned short* aP[AINST];
  int aL[AINST];
  #pragma unroll
  for (int i=0;i<AINST;i++){
    int s = (wave*AINST + i)*64 + lane;
    int row = s >> 2, chn = (s & 3) ^ ((row >> 1) & 3);
    aP[i] = A + (size_t)(row0 + row)*K + chn*8;
    aL[i] = (wave*AINST + i)*1024;
  }
  const unsigned short* bP[BINST];
  int bL[BINST];
  #pragma unroll
  for (int i=0;i<BINST;i++){
    int s = (wave*BINST + i)*64 + lane;
    int row = s >> 2, chn = (s & 3) ^ ((row >> 1) & 3);
    bP[i] = Bt + (size_t)(col0 + row)*K + chn*8;
    bL[i] = (wave*BINST + i)*1024;
  }
  char* ldsA = (char*)sA;
  char* ldsB = (char*)sB;

  auto STAGE = [&](int k0, int buf){
    #pragma unroll
    for (int i=0;i<AINST;i++) gload_lds16(aP[i] + k0, ldsA + buf*ABYTES + aL[i]);
    #pragma unroll
    for (int i=0;i<BINST;i++) gload_lds16(bP[i] + k0, ldsB + buf*BBYTES + bL[i]);
  };

  const int NT = K >> 5;
  const int kch = lane >> 4;
  const int rlo = lane & 15;

  STAGE(0, 0);
  STAGE(32, 1);

  int cur = 0;
  for (int t = 0; t < NT; ++t){
    asm volatile("s_waitcnt lgkmcnt(0)" ::: "memory");
    if (t+1 < NT){
      if constexpr (LPS==4)      asm volatile("s_waitcnt vmcnt(4)" ::: "memory");
      else if constexpr (LPS==3) asm volatile("s_waitcnt vmcnt(3)" ::: "memory");
      else                       asm volatile("s_waitcnt vmcnt(2)" ::: "memory");
    } else {
      asm volatile("s_waitcnt vmcnt(0)" ::: "memory");
    }
    __builtin_amdgcn_sched_barrier(0);
    __builtin_amdgcn_s_barrier();
    __builtin_amdgcn_sched_barrier(0);
    const unsigned short* bA = sA + cur*(TBM*32);
    const unsigned short* bB = sB + cur*(TBN*32);
    short8 af[MFR], bfr[NFR];
    #pragma unroll
    for (int m=0;m<MFR;m++){
      int r = wr + m*16 + rlo;
      af[m] = *(const short8*)(bA + r*32 + ((kch ^ ((r>>1)&3))<<3));
    }
    #pragma unroll
    for (int n=0;n<NFR;n++){
      int r = wc + n*16 + rlo;
      bfr[n] = *(const short8*)(bB + r*32 + ((kch ^ ((r>>1)&3))<<3));
    }
    if (t+2 < NT){
      int nb = cur + 2; if (nb >= 3) nb -= 3;
      STAGE((t+2) << 5, nb);
    }
    __builtin_amdgcn_s_setprio(1);
    #pragma unroll
    for (int m=0;m<MFR;m++)
      #pragma unroll
      for (int n=0;n<NFR;n++)
        acc[m][n] = __builtin_amdgcn_mfma_f32_16x16x32_bf16(af[m], bfr[n], acc[m][n], 0, 0, 0);
    __builtin_amdgcn_s_setprio(0);
    cur += 1; if (cur == 3) cur = 0;
  }
  const int cr = (lane >> 4) * 4;
  const int cc = lane & 15;
  // C store (bf16)
  #pragma unroll
  for (int m=0;m<MFR;m++){
    #pragma unroll
    for (int n=0;n<NFR;n++){
      int col = col0 + wc + n*16 + cc;
      #pragma unroll
      for (int r=0;r<4;r++){
        int row = row0 + wr + m*16 + cr + r;
        if (row < M) Cbf[(size_t)row*FS + col] = f2bf(acc[m][n][r]);
      }
    }
  }
  // fused attention halves for this col-tile (== one full head)
  float asv[NFR], adv[NFR];
  #pragma unroll
  for (int n=0;n<NFR;n++){
    int col = col0 + wc + n*16 + cc;
    asv[n] = asp[col]; adv[n] = adp[col];
  }
  __syncthreads();
  float* part = (float*)sA;        // [2][TBM/2][4][2]
  #pragma unroll
  for (int m=0;m<MFR;m++){
    #pragma unroll
    for (int r=0;r<4;r++){
      float ss = 0.f, sd = 0.f;
      #pragma unroll
      for (int n=0;n<NFR;n++){ float v = acc[m][n][r]; ss += v*asv[n]; sd += v*adv[n]; }
      #pragma unroll
      for (int o=8;o;o>>=1){ ss += __shfl_xor(ss,o); sd += __shfl_xor(sd,o); }
      if (cc == 0){
        int rowLocal = m*16 + cr + r;
        int pidx = ((wave>>2)*(TBM/2) + rowLocal)*8 + (wave&3)*2;
        part[pidx] = ss; part[pidx+1] = sd;
      }
    }
  }
  __syncthreads();
  if (tid < TBM*2){
    int row = tid >> 1, v = tid & 1;
    int base = row*8 + v;
    float s = part[base] + part[base+2] + part[base+4] + part[base+6];
    int grow = row0 + row;
    const int head = colt;
    if (grow < M){
      if (v) a_d[grow*H + head] = s;
      else   a_s[grow*H + head] = s;
    }
  }
}

// ---------- fused softmax + gather, wave-per-node (F=1024, H=4, FS=1024) ----------
// 2-edge ping-pong prefetch (R12 version: best measured).
__global__ __launch_bounds__(256) void k_gatherw(
    const unsigned short* __restrict__ h,
    const float* __restrict__ a_s, const float* __restrict__ a_d,
    const int* __restrict__ ptr, const int* __restrict__ csrc,
    const float* __restrict__ bias, float* __restrict__ out)
{
  __shared__ float sal[4][64*4];
  __shared__ int ssn[4][64];
  const int wid = threadIdx.x >> 6, lane = threadIdx.x & 63;
  const int node = blockIdx.x*4 + wid;
  const int hh = lane >> 4;
  const int beg = ptr[node], deg = ptr[node+1] - beg;
  f32x4 ad4 = *(const f32x4*)(a_d + node*4);
  float acc[16], acc2[16];
  #pragma unroll
  for (int j=0;j<16;j++){ acc[j]=0.f; acc2[j]=0.f; }
  f32x4 denp = {0.f,0.f,0.f,0.f};
  const unsigned short* hb = h + lane*16;

  for (int c0 = 0; c0 < deg; c0 += 64){
    int n = min(64, deg - c0);
    if (lane < n){
      int s = csrc[beg + c0 + lane];
      f32x4 as4 = *(const f32x4*)(a_s + s*4);
      f32x4 e4;
      #pragma unroll
      for (int k2=0;k2<4;k2++){
        float ev = as4[k2] + ad4[k2];
        ev = ev > 0.f ? ev : 0.2f*ev;
        float x = __expf(ev);
        e4[k2] = x;
        denp[k2] += x;
      }
      *(f32x4*)&sal[wid][lane*4] = e4;
      ssn[wid][lane] = s;
    }
    int e = 0;
    if (n >= 2){
      int s0 = ssn[wid][0], s1 = ssn[wid][1];
      float aA = sal[wid][hh], aB = sal[wid][4+hh];
      const unsigned short* p0 = hb + (size_t)s0*1024;
      const unsigned short* p1 = hb + (size_t)s1*1024;
      short8 ca0=*(const short8*)p0, ca1=*(const short8*)(p0+8);
      short8 cb0=*(const short8*)p1, cb1=*(const short8*)(p1+8);
      for (e = 0; e+3 < n; e += 2){
        int s2 = ssn[wid][e+2], s3 = ssn[wid][e+3];
        float nA = sal[wid][(e+2)*4+hh], nB = sal[wid][(e+3)*4+hh];
        const unsigned short* p2 = hb + (size_t)s2*1024;
        const unsigned short* p3 = hb + (size_t)s3*1024;
        short8 na0=*(const short8*)p2, na1=*(const short8*)(p2+8);
        short8 nb0=*(const short8*)p3, nb1=*(const short8*)(p3+8);
        #pragma unroll
        for (int j=0;j<8;j++){ acc[j]   += bf2f((unsigned short)ca0[j])*aA;
                               acc[8+j] += bf2f((unsigned short)ca1[j])*aA; }
        #pragma unroll
        for (int j=0;j<8;j++){ acc2[j]   += bf2f((unsigned short)cb0[j])*aB;
                               acc2[8+j] += bf2f((unsigned short)cb1[j])*aB; }
        ca0=na0; ca1=na1; cb0=nb0; cb1=nb1; aA=nA; aB=nB;
      }
      #pragma unroll
      for (int j=0;j<8;j++){ acc[j]   += bf2f((unsigned short)ca0[j])*aA;
                             acc[8+j] += bf2f((unsigned short)ca1[j])*aA; }
      #pragma unroll
      for (int j=0;j<8;j++){ acc2[j]   += bf2f((unsigned short)cb0[j])*aB;
                             acc2[8+j] += bf2f((unsigned short)cb1[j])*aB; }
      e += 2;
    }
    for (; e < n; ++e){
      int s = ssn[wid][e];
      float al = sal[wid][e*4 + hh];
      const unsigned short* p = hb + (size_t)s*1024;
      short8 u0 = *(const short8*)p, u1 = *(const short8*)(p+8);
      #pragma unroll
      for (int j=0;j<8;j++){ acc[j]   += bf2f((unsigned short)u0[j])*al;
                             acc[8+j] += bf2f((unsigned short)u1[j])*al; }
    }
  }
  #pragma unroll
  for (int o=32;o;o>>=1){
    #pragma unroll
    for (int k2=0;k2<4;k2++) denp[k2] += __shfl_xor(denp[k2], o);
  }
  float inv = 1.f / (denp[hh] + 1e-16f);
  float* op = out + (size_t)node*1024 + lane*16;
  const float* bp = bias + lane*16;
  #pragma unroll
  for (int j=0;j<16;j++) op[j] = (acc[j]+acc2[j])*inv + bp[j];
}

// ---------- fused softmax + gather, wave-per-node (layer 4: F=121, FS=128) ----------
__global__ __launch_bounds__(256) void k_gatherw1(
    const unsigned short* __restrict__ h,
    const float* __restrict__ a_s, const float* __restrict__ a_d,
    const int* __restrict__ ptr, const int* __restrict__ csrc,
    const float* __restrict__ bias, float* __restrict__ out)
{
  __shared__ float sal[4][64];
  __shared__ int ssn[4][64];
  const int wid = threadIdx.x >> 6, lane = threadIdx.x & 63;
  const int node = blockIdx.x*4 + wid;
  const int beg = ptr[node], deg = ptr[node+1] - beg;
  float ad = a_d[node];
  float den = 0.f;
  float acc[2] = {0.f,0.f}, acc2[2] = {0.f,0.f};
  const int c0i = lane*2;
  const unsigned short* hb = h + c0i;

  for (int b0 = 0; b0 < deg; b0 += 64){
    int n = min(64, deg - b0);
    if (lane < n){
      int s = csrc[beg + b0 + lane];
      float ev = a_s[s] + ad;
      ev = ev > 0.f ? ev : 0.2f*ev;
      float x = __expf(ev);
      sal[wid][lane] = x;
      ssn[wid][lane] = s;
      den += x;
    }
    int e = 0;
    for (; e + 1 < n; e += 2){
      int sA_ = ssn[wid][e], sB_ = ssn[wid][e+1];
      float aA = sal[wid][e], aB = sal[wid][e+1];
      const unsigned short* pA = hb + (size_t)sA_*128;
      const unsigned short* pB = hb + (size_t)sB_*128;
      acc[0]  += bf2f(pA[0])*aA; acc[1]  += bf2f(pA[1])*aA;
      acc2[0] += bf2f(pB[0])*aB; acc2[1] += bf2f(pB[1])*aB;
    }
    if (e < n){
      int sA_ = ssn[wid][e];
      float aA = sal[wid][e];
      const unsigned short* pA = hb + (size_t)sA_*128;
      acc[0] += bf2f(pA[0])*aA; acc[1] += bf2f(pA[1])*aA;
    }
  }
  #pragma unroll
  for (int o=32;o;o>>=1) den += __shfl_xor(den, o);
  float inv = 1.f / (den + 1e-16f);
  if (c0i < 121)   out[(size_t)node*121 + c0i]   = (acc[0]+acc2[0])*inv + bias[c0i];
  if (c0i+1 < 121) out[(size_t)node*121 + c0i+1] = (acc[1]+acc2[1])*inv + bias[c0i+1];
}

// ---------- GraphNorm stats (vectorized partials) / coefs / apply+ELU ----------
__global__ void k_gnstats(const float* __restrict__ x, const int* __restrict__ gptr,
                          float* __restrict__ psum, float* __restrict__ psq){
  int g = blockIdx.x, sp = blockIdx.z;
  int c4 = threadIdx.x*4;
  int beg = gptr[g], end = gptr[g+1];
  int n = end - beg;
  int per = (n + NSPLIT - 1) / NSPLIT;
  int nb = beg + sp*per, ne = min(end, nb + per);
  f32x4 s = {0.f,0.f,0.f,0.f}, qv = {0.f,0.f,0.f,0.f};
  for (int i = nb; i < ne; i++){
    f32x4 v = *(const f32x4*)(x + (size_t)i*1024 + c4);
    s += v; qv += v*v;
  }
  int idx = (sp*NG + g)*1024 + c4;
  *(f32x4*)(psum + idx) = s;
  *(f32x4*)(psq + idx) = qv;
}

__global__ void k_coef(const float* __restrict__ psum, const float* __restrict__ psq,
                       const int* __restrict__ gptr,
                       const float* __restrict__ w, const float* __restrict__ b, const float* __restrict__ ms,
                       float* __restrict__ cA, float* __restrict__ cB){
  int i = blockIdx.x*256 + threadIdx.x;
  if (i >= NG*1024) return;
  int g = i >> 10, c = i & 1023;
  float cntf = (float)(gptr[g+1] - gptr[g]);
  float sm = 0.f, sq = 0.f;
  #pragma unroll
  for (int sp=0; sp<NSPLIT; sp++){
    sm += psum[(sp*NG + g)*1024 + c];
    sq += psq[(sp*NG + g)*1024 + c];
  }
  float m = sm / cntf;
  float s = ms[c];
  float ex2 = sq / cntf;
  float var = ex2 - 2.f*s*m*m + s*s*m*m;
  float inv = rsqrtf(var + 1e-5f);
  float wa = w[c]*inv;
  cA[i] = wa;
  cB[i] = b[c] - wa*m*s;
}

__global__ void k_applyelu(const float* __restrict__ x, const int* __restrict__ batch,
                           const float* __restrict__ cA, const float* __restrict__ cB,
                           unsigned short* __restrict__ obf){
  int i = blockIdx.x*256 + threadIdx.x;        // over NN*256
  if (i >= NN*256) return;
  int node = i >> 8;
  int c4 = (i & 255)*4;
  int g = batch[node];
  f32x4 v = *(const f32x4*)(x + (size_t)node*1024 + c4);
  f32x4 a = *(const f32x4*)(cA + g*1024 + c4);
  f32x4 b = *(const f32x4*)(cB + g*1024 + c4);
  us4 o;
  #pragma unroll
  for (int j=0;j<4;j++){
    float y = a[j]*v[j] + b[j];
    y = y > 0.f ? y : expm1f(y);
    o[j] = f2bf(y);
  }
  *(us4*)(obf + (size_t)node*1024 + c4) = o;
}

// ---------- orchestration ----------
extern "C" void kernel_launch(void* const* d_in, const int* in_sizes, int n_in,
                              void* d_out, int out_size, void* d_ws, size_t ws_size,
                              hipStream_t stream){
  (void)in_sizes; (void)n_in; (void)out_size; (void)ws_size;
  const float* x     = (const float*)d_in[0];
  const int*   ei    = (const int*)d_in[1];
  const int*   batch = (const int*)d_in[2];
  const float* W[4]  = {(const float*)d_in[3],  (const float*)d_in[7],  (const float*)d_in[11], (const float*)d_in[15]};
  const float* AS[4] = {(const float*)d_in[4],  (const float*)d_in[8],  (const float*)d_in[12], (const float*)d_in[16]};
  const float* AD[4] = {(const float*)d_in[5],  (const float*)d_in[9],  (const float*)d_in[13], (const float*)d_in[17]};
  const float* BI[4] = {(const float*)d_in[6],  (const float*)d_in[10], (const float*)d_in[14], (const float*)d_in[18]};
  const float* GW[3] = {(const float*)d_in[19], (const float*)d_in[22], (const float*)d_in[25]};
  const float* GB[3] = {(const float*)d_in[20], (const float*)d_in[23], (const float*)d_in[26]};
  const float* GA[3] = {(const float*)d_in[21], (const float*)d_in[24], (const float*)d_in[27]};

  float* ws   = (float*)d_ws;
  float* bufB = ws;                                  // [NN,1024] f32
  float* a_s  = bufB + (size_t)NN*1024;              // [NN,4]
  float* a_d  = a_s + (size_t)NN*4;                  // [NN,4]
  float* psum = a_d + (size_t)NN*4;                  // [NSPLIT,NG,1024]
  float* psq  = psum + (size_t)NSPLIT*NG*1024;       // [NSPLIT,NG,1024]
  float* cA   = psq  + (size_t)NSPLIT*NG*1024;       // [NG,1024]
  float* cB   = cA   + (size_t)NG*1024;              // [NG,1024]
  float* asp4 = cB   + (size_t)NG*1024;              // [128]
  float* adp4 = asp4 + 128;                          // [128]
  int* ptr  = (int*)(adp4 + 128);                    // [NN+1]
  int* fill = ptr + (NN + 8);                        // [NN+1]
  int* csrc = fill + (NN + 8);                       // [E2]
  int* gptr = csrc + E2;                             // [NG+1] (pad 24)
  unsigned short* abf = (unsigned short*)(gptr + 24);// [MPAD,1024] bf16 (xbf aliases start)
  unsigned short* xbf = abf;                         // [MPAD,64] bf16 (dead after L0 gemm)
  unsigned short* hbf = abf + (size_t)MPAD*1024;     // [NN,1024] bf16
  unsigned short* wt  = hbf + (size_t)NN*1024;       // [WTT] bf16 (all 4 layers)

  hipMemsetAsync(fill, 0, sizeof(int)*(NN+1), stream);
  k_gptr<<<1, 32, 0, stream>>>(batch, gptr);
  k_count<<<(E2+255)/256, 256, 0, stream>>>(ei, fill);
  k_scan<<<1, 256, 0, stream>>>(fill, ptr);
  k_copy<<<(NN+255)/256, 256, 0, stream>>>(ptr, fill);
  k_scatter<<<(E2+255)/256, 256, 0, stream>>>(ei, fill, csrc);
  k_xconv<<<(MPAD*64+255)/256, 256, 0, stream>>>(x, xbf);
  k_wconvall<<<(WTT+255)/256, 256, 0, stream>>>(W[0], W[1], W[2], W[3], wt);
  k_attpad4<<<1, 128, 0, stream>>>(AS[3], AD[3], asp4, adp4);

  const int Kp[4]  = {64, 1024, 1024, 1024};
  const int Np[4]  = {1024, 1024, 1024, 128};
  const int Woff[4] = {WT0, WT1, WT2, WT3};
  for (int li = 0; li < 4; ++li){
    int FS = Np[li];
    const unsigned short* Ain = (li == 0) ? xbf : abf;
    const unsigned short* Wt = wt + Woff[li];
    if (li < 3){
      int ncb = 4;                          // 4 col-tiles of 256 (one head each)
      int nwg = (MPAD/128) * ncb;           // 80*4 = 320 blocks (all CUs, 2/CU on 64)
      k_gemm256<128,256><<<nwg, 512, 0, stream>>>(Ain, Wt, hbf, AS[li], AD[li], a_s, a_d,
                                                  NN, Kp[li], FS, ncb, 4);
      k_gatherw<<<NN/4, 256, 0, stream>>>(hbf, a_s, a_d, ptr, csrc, BI[li], bufB);
      k_gnstats<<<dim3(NG, 1, NSPLIT), 256, 0, stream>>>(bufB, gptr, psum, psq);
      k_coef<<<(NG*1024 + 255)/256, 256, 0, stream>>>(psum, psq, gptr, GW[li], GB[li], GA[li], cA, cB);
      k_applyelu<<<(NN*256 + 255)/256, 256, 0, stream>>>(bufB, batch, cA, cB, abf);
    } else {
      int ncb = 1;
      int nwg = (MPAD/256) * ncb;           // 40 blocks
      k_gemm256<256,128><<<nwg, 512, 0, stream>>>(Ain, Wt, hbf, asp4, adp4, a_s, a_d,
                                                  NN, Kp[li], FS, ncb, 1);
      k_gatherw1<<<NN/4, 256, 0, stream>>>(hbf, a_s, a_d, ptr, csrc, BI[li], (float*)d_out);
    }
  }
}

// Round 16
// 445.450 us; speedup vs baseline: 1.1502x; 1.0830x over previous
//
#include <hip/hip_runtime.h>
#include <math.h>

#define NN 10000
#define NE 160000
#define E2 (NE + NN)
#define NG 20
#define MPAD 10240   // 80*128 = 40*256
#define NSPLIT 16

typedef __attribute__((ext_vector_type(8))) short short8;
typedef __attribute__((ext_vector_type(4))) float f32x4;
typedef __attribute__((ext_vector_type(4))) unsigned short us4;

// ---------- helpers ----------
__device__ inline unsigned short f2bf(float f){
  unsigned u = __float_as_uint(f);
  unsigned r = u + 0x7FFFu + ((u >> 16) & 1u);
  return (unsigned short)(r >> 16);
}
__device__ inline float bf2f(unsigned short h){ return __uint_as_float(((unsigned)h) << 16); }

__device__ inline void gload_lds16(const void* g, void* l){
  __builtin_amdgcn_global_load_lds((const __attribute__((address_space(1))) void*)g,
                                   (__attribute__((address_space(3))) void*)l, 16, 0, 0);
}

// ---------- graph boundary (batch is sorted) ----------
__global__ void k_gptr(const int* __restrict__ batch, int* __restrict__ gptr){
  int g = threadIdx.x;
  if (g > NG) return;
  int lo = 0, hi = NN;
  while (lo < hi){ int mid = (lo+hi)>>1; if (batch[mid] < g) lo = mid+1; else hi = mid; }
  gptr[g] = lo;
}

// ---------- CSR build (by dst, self-loops appended) ----------
__global__ void k_count(const int* __restrict__ ei, int* __restrict__ cnt){
  int e = blockIdx.x*256 + threadIdx.x;
  if (e >= E2) return;
  int d = (e < NE) ? ei[NE + e] : (e - NE);
  atomicAdd(&cnt[d], 1);
}

__global__ void k_scan(const int* __restrict__ cnt, int* __restrict__ ptr){
  __shared__ int tpre[256];
  __shared__ int tsum[256];
  int tid = threadIdx.x;
  const int per = (NN + 255)/256;
  int base = tid*per;
  int s = 0;
  for (int i=0;i<per;i++){ int idx=base+i; if (idx<NN) s += cnt[idx]; }
  tsum[tid] = s;
  __syncthreads();
  if (tid == 0){
    int run = 0;
    for (int i=0;i<256;i++){ tpre[i]=run; run += tsum[i]; }
    ptr[NN] = run;
  }
  __syncthreads();
  int run = tpre[tid];
  for (int i=0;i<per;i++){ int idx=base+i; if (idx<NN){ ptr[idx]=run; run += cnt[idx]; } }
}

__global__ void k_copy(const int* __restrict__ src, int* __restrict__ dst){
  int i = blockIdx.x*256 + threadIdx.x;
  if (i < NN) dst[i] = src[i];
}

__global__ void k_scatter(const int* __restrict__ ei, int* __restrict__ fill, int* __restrict__ csrc){
  int e = blockIdx.x*256 + threadIdx.x;
  if (e >= E2) return;
  int s, d;
  if (e < NE){ s = ei[e]; d = ei[NE + e]; } else { s = d = e - NE; }
  int pos = atomicAdd(&fill[d], 1);
  csrc[pos] = s;
}

// ---------- merged setup: W transposes + x pad/convert + L4 att pad ----------
#define WT0 0
#define WT1 65536
#define WT2 1114112
#define WT3 2162688
#define WTT 2293760
#define XS  (MPAD*64)
__global__ void k_setup(const float* __restrict__ W0, const float* __restrict__ W1,
                        const float* __restrict__ W2, const float* __restrict__ W3,
                        const float* __restrict__ x,
                        const float* __restrict__ AS3, const float* __restrict__ AD3,
                        unsigned short* __restrict__ wt, unsigned short* __restrict__ xbf,
                        float* __restrict__ asp4, float* __restrict__ adp4){
  int i = blockIdx.x*256 + threadIdx.x;
  if (i < WTT){
    const float* W; int K, N, Kpad, off;
    if (i < WT1){ W=W0; K=50; N=1024; Kpad=64; off=WT0; }
    else if (i < WT2){ W=W1; K=1024; N=1024; Kpad=1024; off=WT1; }
    else if (i < WT3){ W=W2; K=1024; N=1024; Kpad=1024; off=WT2; }
    else { W=W3; K=1024; N=121; Kpad=1024; off=WT3; }
    int j = i - off;
    int nn = j / Kpad, kk = j - nn*Kpad;
    float v = (nn < N && kk < K) ? W[(size_t)kk*N + nn] : 0.f;
    wt[i] = f2bf(v);
  } else if (i < WTT + XS){
    int j = i - WTT;
    int r = j >> 6, c = j & 63;
    float v = (r < NN && c < 50) ? x[r*50 + c] : 0.f;
    xbf[j] = f2bf(v);
  } else if (i < WTT + XS + 128){
    int j = i - WTT - XS;
    asp4[j] = (j < 121) ? AS3[j] : 0.f;
    adp4[j] = (j < 121) ? AD3[j] : 0.f;
  }
}

// ---------- bf16 MFMA GEMM: TBM x TBN tile, 512 threads (8 waves, 2x4) ----------
// R12's measured-best schedule: 3-buffer LDS, lgkmcnt drain + counted vmcnt,
// one barrier per K-step, chunk-swizzled LDS. Epilogue: block-local fused
// attention halves (col-tile == one full head), plain stores, no atomics.
template<int TBM, int TBN>
__global__ __launch_bounds__(512, 4) void k_gemm256(
    const unsigned short* __restrict__ A,
    const unsigned short* __restrict__ Bt,
    unsigned short* __restrict__ Cbf,
    const float* __restrict__ asp, const float* __restrict__ adp,
    float* __restrict__ a_s, float* __restrict__ a_d,
    int M, int K, int FS, int ncb, int H)
{
  constexpr int MFR = TBM/32;
  constexpr int NFR = TBN/64;
  constexpr int ABYTES = TBM*64;
  constexpr int BBYTES = TBN*64;
  constexpr int AINST = TBM/128;
  constexpr int BINST = TBN/128;
  constexpr int LPS = AINST + BINST;
  __shared__ unsigned short sA[3*TBM*32];
  __shared__ unsigned short sB[3*TBN*32];
  const int tid = threadIdx.x;
  const int wave = tid >> 6;
  const int lane = tid & 63;
  const int nwg = gridDim.x;
  const int q = nwg >> 3, rmod = nwg & 7;
  const int xcd = blockIdx.x & 7, idx = blockIdx.x >> 3;
  const int wg = (xcd < rmod) ? (xcd*(q+1) + idx) : (rmod*(q+1) + (xcd - rmod)*q + idx);
  const int rowt = wg / ncb;
  const int colt = wg - rowt*ncb;
  const int row0 = rowt * TBM;
  const int col0 = colt * TBN;
  const int wr = (wave >> 2) * (TBM/2);
  const int wc = (wave & 3) * (TBN/4);
  f32x4 acc[MFR][NFR];
  #pragma unroll
  for (int i=0;i<MFR;i++)
    #pragma unroll
    for (int j=0;j<NFR;j++){ acc[i][j][0]=0.f; acc[i][j][1]=0.f; acc[i][j][2]=0.f; acc[i][j][3]=0.f; }

  const unsigned short* aP[AINST];
  int aL[AINST];
  #pragma unroll
  for (int i=0;i<AINST;i++){
    int s = (wave*AINST + i)*64 + lane;
    int row = s >> 2, chn = (s & 3) ^ ((row >> 1) & 3);
    aP[i] = A + (size_t)(row0 + row)*K + chn*8;
    aL[i] = (wave*AINST + i)*1024;
  }
  const unsigned short* bP[BINST];
  int bL[BINST];
  #pragma unroll
  for (int i=0;i<BINST;i++){
    int s = (wave*BINST + i)*64 + lane;
    int row = s >> 2, chn = (s & 3) ^ ((row >> 1) & 3);
    bP[i] = Bt + (size_t)(col0 + row)*K + chn*8;
    bL[i] = (wave*BINST + i)*1024;
  }
  char* ldsA = (char*)sA;
  char* ldsB = (char*)sB;

  auto STAGE = [&](int k0, int buf){
    #pragma unroll
    for (int i=0;i<AINST;i++) gload_lds16(aP[i] + k0, ldsA + buf*ABYTES + aL[i]);
    #pragma unroll
    for (int i=0;i<BINST;i++) gload_lds16(bP[i] + k0, ldsB + buf*BBYTES + bL[i]);
  };

  const int NT = K >> 5;
  const int kch = lane >> 4;
  const int rlo = lane & 15;

  STAGE(0, 0);
  STAGE(32, 1);

  int cur = 0;
  for (int t = 0; t < NT; ++t){
    asm volatile("s_waitcnt lgkmcnt(0)" ::: "memory");
    if (t+1 < NT){
      if constexpr (LPS==4)      asm volatile("s_waitcnt vmcnt(4)" ::: "memory");
      else if constexpr (LPS==3) asm volatile("s_waitcnt vmcnt(3)" ::: "memory");
      else                       asm volatile("s_waitcnt vmcnt(2)" ::: "memory");
    } else {
      asm volatile("s_waitcnt vmcnt(0)" ::: "memory");
    }
    __builtin_amdgcn_sched_barrier(0);
    __builtin_amdgcn_s_barrier();
    __builtin_amdgcn_sched_barrier(0);
    const unsigned short* bA = sA + cur*(TBM*32);
    const unsigned short* bB = sB + cur*(TBN*32);
    short8 af[MFR], bfr[NFR];
    #pragma unroll
    for (int m=0;m<MFR;m++){
      int r = wr + m*16 + rlo;
      af[m] = *(const short8*)(bA + r*32 + ((kch ^ ((r>>1)&3))<<3));
    }
    #pragma unroll
    for (int n=0;n<NFR;n++){
      int r = wc + n*16 + rlo;
      bfr[n] = *(const short8*)(bB + r*32 + ((kch ^ ((r>>1)&3))<<3));
    }
    if (t+2 < NT){
      int nb = cur + 2; if (nb >= 3) nb -= 3;
      STAGE((t+2) << 5, nb);
    }
    __builtin_amdgcn_s_setprio(1);
    #pragma unroll
    for (int m=0;m<MFR;m++)
      #pragma unroll
      for (int n=0;n<NFR;n++)
        acc[m][n] = __builtin_amdgcn_mfma_f32_16x16x32_bf16(af[m], bfr[n], acc[m][n], 0, 0, 0);
    __builtin_amdgcn_s_setprio(0);
    cur += 1; if (cur == 3) cur = 0;
  }
  const int cr = (lane >> 4) * 4;
  const int cc = lane & 15;
  // C store (bf16)
  #pragma unroll
  for (int m=0;m<MFR;m++){
    #pragma unroll
    for (int n=0;n<NFR;n++){
      int col = col0 + wc + n*16 + cc;
      #pragma unroll
      for (int r=0;r<4;r++){
        int row = row0 + wr + m*16 + cr + r;
        if (row < M) Cbf[(size_t)row*FS + col] = f2bf(acc[m][n][r]);
      }
    }
  }
  // fused attention halves for this col-tile (== one full head)
  float asv[NFR], adv[NFR];
  #pragma unroll
  for (int n=0;n<NFR;n++){
    int col = col0 + wc + n*16 + cc;
    asv[n] = asp[col]; adv[n] = adp[col];
  }
  __syncthreads();
  float* part = (float*)sA;        // [2][TBM/2][4][2]
  #pragma unroll
  for (int m=0;m<MFR;m++){
    #pragma unroll
    for (int r=0;r<4;r++){
      float ss = 0.f, sd = 0.f;
      #pragma unroll
      for (int n=0;n<NFR;n++){ float v = acc[m][n][r]; ss += v*asv[n]; sd += v*adv[n]; }
      #pragma unroll
      for (int o=8;o;o>>=1){ ss += __shfl_xor(ss,o); sd += __shfl_xor(sd,o); }
      if (cc == 0){
        int rowLocal = m*16 + cr + r;
        int pidx = ((wave>>2)*(TBM/2) + rowLocal)*8 + (wave&3)*2;
        part[pidx] = ss; part[pidx+1] = sd;
      }
    }
  }
  __syncthreads();
  if (tid < TBM*2){
    int row = tid >> 1, v = tid & 1;
    int base = row*8 + v;
    float s = part[base] + part[base+2] + part[base+4] + part[base+6];
    int grow = row0 + row;
    const int head = colt;
    if (grow < M){
      if (v) a_d[grow*H + head] = s;
      else   a_s[grow*H + head] = s;
    }
  }
}

// ---------- fused softmax + gather, wave-per-node (F=1024, H=4, FS=1024) ----------
// 2-edge ping-pong prefetch (R12 version: best measured).
__global__ __launch_bounds__(256) void k_gatherw(
    const unsigned short* __restrict__ h,
    const float* __restrict__ a_s, const float* __restrict__ a_d,
    const int* __restrict__ ptr, const int* __restrict__ csrc,
    const float* __restrict__ bias, float* __restrict__ out)
{
  __shared__ float sal[4][64*4];
  __shared__ int ssn[4][64];
  const int wid = threadIdx.x >> 6, lane = threadIdx.x & 63;
  const int node = blockIdx.x*4 + wid;
  const int hh = lane >> 4;
  const int beg = ptr[node], deg = ptr[node+1] - beg;
  f32x4 ad4 = *(const f32x4*)(a_d + node*4);
  float acc[16], acc2[16];
  #pragma unroll
  for (int j=0;j<16;j++){ acc[j]=0.f; acc2[j]=0.f; }
  f32x4 denp = {0.f,0.f,0.f,0.f};
  const unsigned short* hb = h + lane*16;

  for (int c0 = 0; c0 < deg; c0 += 64){
    int n = min(64, deg - c0);
    if (lane < n){
      int s = csrc[beg + c0 + lane];
      f32x4 as4 = *(const f32x4*)(a_s + s*4);
      f32x4 e4;
      #pragma unroll
      for (int k2=0;k2<4;k2++){
        float ev = as4[k2] + ad4[k2];
        ev = ev > 0.f ? ev : 0.2f*ev;
        float x = __expf(ev);
        e4[k2] = x;
        denp[k2] += x;
      }
      *(f32x4*)&sal[wid][lane*4] = e4;
      ssn[wid][lane] = s;
    }
    int e = 0;
    if (n >= 2){
      int s0 = ssn[wid][0], s1 = ssn[wid][1];
      float aA = sal[wid][hh], aB = sal[wid][4+hh];
      const unsigned short* p0 = hb + (size_t)s0*1024;
      const unsigned short* p1 = hb + (size_t)s1*1024;
      short8 ca0=*(const short8*)p0, ca1=*(const short8*)(p0+8);
      short8 cb0=*(const short8*)p1, cb1=*(const short8*)(p1+8);
      for (e = 0; e+3 < n; e += 2){
        int s2 = ssn[wid][e+2], s3 = ssn[wid][e+3];
        float nA = sal[wid][(e+2)*4+hh], nB = sal[wid][(e+3)*4+hh];
        const unsigned short* p2 = hb + (size_t)s2*1024;
        const unsigned short* p3 = hb + (size_t)s3*1024;
        short8 na0=*(const short8*)p2, na1=*(const short8*)(p2+8);
        short8 nb0=*(const short8*)p3, nb1=*(const short8*)(p3+8);
        #pragma unroll
        for (int j=0;j<8;j++){ acc[j]   += bf2f((unsigned short)ca0[j])*aA;
                               acc[8+j] += bf2f((unsigned short)ca1[j])*aA; }
        #pragma unroll
        for (int j=0;j<8;j++){ acc2[j]   += bf2f((unsigned short)cb0[j])*aB;
                               acc2[8+j] += bf2f((unsigned short)cb1[j])*aB; }
        ca0=na0; ca1=na1; cb0=nb0; cb1=nb1; aA=nA; aB=nB;
      }
      #pragma unroll
      for (int j=0;j<8;j++){ acc[j]   += bf2f((unsigned short)ca0[j])*aA;
                             acc[8+j] += bf2f((unsigned short)ca1[j])*aA; }
      #pragma unroll
      for (int j=0;j<8;j++){ acc2[j]   += bf2f((unsigned short)cb0[j])*aB;
                             acc2[8+j] += bf2f((unsigned short)cb1[j])*aB; }
      e += 2;
    }
    for (; e < n; ++e){
      int s = ssn[wid][e];
      float al = sal[wid][e*4 + hh];
      const unsigned short* p = hb + (size_t)s*1024;
      short8 u0 = *(const short8*)p, u1 = *(const short8*)(p+8);
      #pragma unroll
      for (int j=0;j<8;j++){ acc[j]   += bf2f((unsigned short)u0[j])*al;
                             acc[8+j] += bf2f((unsigned short)u1[j])*al; }
    }
  }
  #pragma unroll
  for (int o=32;o;o>>=1){
    #pragma unroll
    for (int k2=0;k2<4;k2++) denp[k2] += __shfl_xor(denp[k2], o);
  }
  float inv = 1.f / (denp[hh] + 1e-16f);
  float* op = out + (size_t)node*1024 + lane*16;
  const float* bp = bias + lane*16;
  #pragma unroll
  for (int j=0;j<16;j++) op[j] = (acc[j]+acc2[j])*inv + bp[j];
}

// ---------- fused softmax + gather, wave-per-node (layer 4: F=121, FS=128) ----------
__global__ __launch_bounds__(256) void k_gatherw1(
    const unsigned short* __restrict__ h,
    const float* __restrict__ a_s, const float* __restrict__ a_d,
    const int* __restrict__ ptr, const int* __restrict__ csrc,
    const float* __restrict__ bias, float* __restrict__ out)
{
  __shared__ float sal[4][64];
  __shared__ int ssn[4][64];
  const int wid = threadIdx.x >> 6, lane = threadIdx.x & 63;
  const int node = blockIdx.x*4 + wid;
  const int beg = ptr[node], deg = ptr[node+1] - beg;
  float ad = a_d[node];
  float den = 0.f;
  float acc[2] = {0.f,0.f}, acc2[2] = {0.f,0.f};
  const int c0i = lane*2;
  const unsigned short* hb = h + c0i;

  for (int b0 = 0; b0 < deg; b0 += 64){
    int n = min(64, deg - b0);
    if (lane < n){
      int s = csrc[beg + b0 + lane];
      float ev = a_s[s] + ad;
      ev = ev > 0.f ? ev : 0.2f*ev;
      float x = __expf(ev);
      sal[wid][lane] = x;
      ssn[wid][lane] = s;
      den += x;
    }
    int e = 0;
    for (; e + 1 < n; e += 2){
      int sA_ = ssn[wid][e], sB_ = ssn[wid][e+1];
      float aA = sal[wid][e], aB = sal[wid][e+1];
      unsigned uA = *(const unsigned*)(hb + (size_t)sA_*128);
      unsigned uB = *(const unsigned*)(hb + (size_t)sB_*128);
      acc[0]  += bf2f((unsigned short)(uA & 0xFFFF))*aA;
      acc[1]  += bf2f((unsigned short)(uA >> 16))*aA;
      acc2[0] += bf2f((unsigned short)(uB & 0xFFFF))*aB;
      acc2[1] += bf2f((unsigned short)(uB >> 16))*aB;
    }
    if (e < n){
      int sA_ = ssn[wid][e];
      float aA = sal[wid][e];
      unsigned uA = *(const unsigned*)(hb + (size_t)sA_*128);
      acc[0] += bf2f((unsigned short)(uA & 0xFFFF))*aA;
      acc[1] += bf2f((unsigned short)(uA >> 16))*aA;
    }
  }
  #pragma unroll
  for (int o=32;o;o>>=1) den += __shfl_xor(den, o);
  float inv = 1.f / (den + 1e-16f);
  if (c0i < 121)   out[(size_t)node*121 + c0i]   = (acc[0]+acc2[0])*inv + bias[c0i];
  if (c0i+1 < 121) out[(size_t)node*121 + c0i+1] = (acc[1]+acc2[1])*inv + bias[c0i+1];
}

// ---------- GraphNorm stats (vectorized partials) / coefs / apply+ELU ----------
__global__ void k_gnstats(const float* __restrict__ x, const int* __restrict__ gptr,
                          float* __restrict__ psum, float* __restrict__ psq){
  int g = blockIdx.x, sp = blockIdx.z;
  int c4 = threadIdx.x*4;
  int beg = gptr[g], end = gptr[g+1];
  int n = end - beg;
  int per = (n + NSPLIT - 1) / NSPLIT;
  int nb = beg + sp*per, ne = min(end, nb + per);
  f32x4 s = {0.f,0.f,0.f,0.f}, qv = {0.f,0.f,0.f,0.f};
  for (int i = nb; i < ne; i++){
    f32x4 v = *(const f32x4*)(x + (size_t)i*1024 + c4);
    s += v; qv += v*v;
  }
  int idx = (sp*NG + g)*1024 + c4;
  *(f32x4*)(psum + idx) = s;
  *(f32x4*)(psq + idx) = qv;
}

__global__ void k_coef(const float* __restrict__ psum, const float* __restrict__ psq,
                       const int* __restrict__ gptr,
                       const float* __restrict__ w, const float* __restrict__ b, const float* __restrict__ ms,
                       float* __restrict__ cA, float* __restrict__ cB){
  int i = blockIdx.x*256 + threadIdx.x;
  if (i >= NG*1024) return;
  int g = i >> 10, c = i & 1023;
  float cntf = (float)(gptr[g+1] - gptr[g]);
  float sm = 0.f, sq = 0.f;
  #pragma unroll
  for (int sp=0; sp<NSPLIT; sp++){
    sm += psum[(sp*NG + g)*1024 + c];
    sq += psq[(sp*NG + g)*1024 + c];
  }
  float m = sm / cntf;
  float s = ms[c];
  float ex2 = sq / cntf;
  float var = ex2 - 2.f*s*m*m + s*s*m*m;
  float inv = rsqrtf(var + 1e-5f);
  float wa = w[c]*inv;
  cA[i] = wa;
  cB[i] = b[c] - wa*m*s;
}

__global__ void k_applyelu(const float* __restrict__ x, const int* __restrict__ batch,
                           const float* __restrict__ cA, const float* __restrict__ cB,
                           unsigned short* __restrict__ obf){
  int i = blockIdx.x*256 + threadIdx.x;        // over NN*256
  if (i >= NN*256) return;
  int node = i >> 8;
  int c4 = (i & 255)*4;
  int g = batch[node];
  f32x4 v = *(const f32x4*)(x + (size_t)node*1024 + c4);
  f32x4 a = *(const f32x4*)(cA + g*1024 + c4);
  f32x4 b = *(const f32x4*)(cB + g*1024 + c4);
  us4 o;
  #pragma unroll
  for (int j=0;j<4;j++){
    float y = a[j]*v[j] + b[j];
    y = y > 0.f ? y : expm1f(y);
    o[j] = f2bf(y);
  }
  *(us4*)(obf + (size_t)node*1024 + c4) = o;
}

// ---------- orchestration ----------
extern "C" void kernel_launch(void* const* d_in, const int* in_sizes, int n_in,
                              void* d_out, int out_size, void* d_ws, size_t ws_size,
                              hipStream_t stream){
  (void)in_sizes; (void)n_in; (void)out_size; (void)ws_size;
  const float* x     = (const float*)d_in[0];
  const int*   ei    = (const int*)d_in[1];
  const int*   batch = (const int*)d_in[2];
  const float* W[4]  = {(const float*)d_in[3],  (const float*)d_in[7],  (const float*)d_in[11], (const float*)d_in[15]};
  const float* AS[4] = {(const float*)d_in[4],  (const float*)d_in[8],  (const float*)d_in[12], (const float*)d_in[16]};
  const float* AD[4] = {(const float*)d_in[5],  (const float*)d_in[9],  (const float*)d_in[13], (const float*)d_in[17]};
  const float* BI[4] = {(const float*)d_in[6],  (const float*)d_in[10], (const float*)d_in[14], (const float*)d_in[18]};
  const float* GW[3] = {(const float*)d_in[19], (const float*)d_in[22], (const float*)d_in[25]};
  const float* GB[3] = {(const float*)d_in[20], (const float*)d_in[23], (const float*)d_in[26]};
  const float* GA[3] = {(const float*)d_in[21], (const float*)d_in[24], (const float*)d_in[27]};

  float* ws   = (float*)d_ws;
  float* bufB = ws;                                  // [NN,1024] f32
  float* a_s  = bufB + (size_t)NN*1024;              // [NN,4]
  float* a_d  = a_s + (size_t)NN*4;                  // [NN,4]
  float* psum = a_d + (size_t)NN*4;                  // [NSPLIT,NG,1024]
  float* psq  = psum + (size_t)NSPLIT*NG*1024;       // [NSPLIT,NG,1024]
  float* cA   = psq  + (size_t)NSPLIT*NG*1024;       // [NG,1024]
  float* cB   = cA   + (size_t)NG*1024;              // [NG,1024]
  float* asp4 = cB   + (size_t)NG*1024;              // [128]
  float* adp4 = asp4 + 128;                          // [128]
  int* ptr  = (int*)(adp4 + 128);                    // [NN+1]
  int* fill = ptr + (NN + 8);                        // [NN+1]
  int* csrc = fill + (NN + 8);                       // [E2]
  int* gptr = csrc + E2;                             // [NG+1] (pad 24)
  unsigned short* abf = (unsigned short*)(gptr + 24);// [MPAD,1024] bf16 (xbf aliases start)
  unsigned short* xbf = abf;                         // [MPAD,64] bf16 (dead after L0 gemm)
  unsigned short* hbf = abf + (size_t)MPAD*1024;     // [NN,1024] bf16
  unsigned short* wt  = hbf + (size_t)NN*1024;       // [WTT] bf16 (all 4 layers)

  hipMemsetAsync(fill, 0, sizeof(int)*(NN+1), stream);
  k_gptr<<<1, 32, 0, stream>>>(batch, gptr);
  k_count<<<(E2+255)/256, 256, 0, stream>>>(ei, fill);
  k_scan<<<1, 256, 0, stream>>>(fill, ptr);
  k_copy<<<(NN+255)/256, 256, 0, stream>>>(ptr, fill);
  k_scatter<<<(E2+255)/256, 256, 0, stream>>>(ei, fill, csrc);
  k_setup<<<(WTT + XS + 128 + 255)/256, 256, 0, stream>>>(W[0], W[1], W[2], W[3], x,
                                                          AS[3], AD[3], wt, xbf, asp4, adp4);

  const int Kp[4]  = {64, 1024, 1024, 1024};
  const int Np[4]  = {1024, 1024, 1024, 128};
  const int Woff[4] = {WT0, WT1, WT2, WT3};
  for (int li = 0; li < 4; ++li){
    int FS = Np[li];
    const unsigned short* Ain = (li == 0) ? xbf : abf;
    const unsigned short* Wt = wt + Woff[li];
    if (li < 3){
      int ncb = 4;                          // 4 col-tiles of 256 (one head each)
      int nwg = (MPAD/128) * ncb;           // 80*4 = 320 blocks (all CUs, 2/CU on 64)
      k_gemm256<128,256><<<nwg, 512, 0, stream>>>(Ain, Wt, hbf, AS[li], AD[li], a_s, a_d,
                                                  NN, Kp[li], FS, ncb, 4);
      k_gatherw<<<NN/4, 256, 0, stream>>>(hbf, a_s, a_d, ptr, csrc, BI[li], bufB);
      k_gnstats<<<dim3(NG, 1, NSPLIT), 256, 0, stream>>>(bufB, gptr, psum, psq);
      k_coef<<<(NG*1024 + 255)/256, 256, 0, stream>>>(psum, psq, gptr, GW[li], GB[li], GA[li], cA, cB);
      k_applyelu<<<(NN*256 + 255)/256, 256, 0, stream>>>(bufB, batch, cA, cB, abf);
    } else {
      int ncb = 1;                          // single 128-col tile (the whole head)
      int nwg = (MPAD/128) * ncb;           // 80 blocks (2x CU coverage vs 40)
      k_gemm256<128,128><<<nwg, 512, 0, stream>>>(Ain, Wt, hbf, asp4, adp4, a_s, a_d,
                                                  NN, Kp[li], FS, ncb, 1);
      k_gatherw1<<<NN/4, 256, 0, stream>>>(hbf, a_s, a_d, ptr, csrc, BI[li], (float*)d_out);
    }
  }
}